// Round 9
// baseline (183.270 us; speedup 1.0000x reference)
//
#include <hip/hip_runtime.h>
#include <hip/hip_bf16.h>

// out[b,o,hw] = sum_c W[o,c] * relu(x[b,c,hw]*scale[c] + shift[c])
// B=256, Cin=2112, Cout=192, HW=49, fp32 in HBM, bf16 MFMA internally.
//
// R16 = R15 resubmitted verbatim (round-8 bench died to the same
// container-acquisition flake as round 3; kernel audited: barriers
// uniform, workspace 20.3MB < harness-verified 54MB, x reads end at
// exactly CIN*HWS-1, add grid exact). K-SPLIT x2, atomic-free: grid
// 512 = (image, K-half); two co-resident 8-wave blocks per CU in
// INDEPENDENT barrier domains, each running the R8-proven pipeline over
// its own 33-granule half (1056 ch). Partials -> workspace; f32x4 add
// kernel (29 MB, ~5us) sums into out. Tests the one clean unexplored
// lever: cross-block TLP filling the latency stalls that kept every
// 8-wave/CU variant at ~55us with all pipes <20% busy.

#define CIN    2112
#define COUT   192
#define HWS    49
#define BK     32
#define NK32   (CIN / BK)          // 66 granules total
#define HALF   (NK32 / 2)          // 33 granules per K-half
#define CHALF  (HALF * BK)         // 1056 channels per half
#define EPSV   1e-5f
#define SLAB   (BK * HWS)          // 1568 elems per granule slab
#define OUTEL  (COUT * HWS)        // 9408 floats per image

typedef __bf16 bf16;
typedef __attribute__((ext_vector_type(8))) __bf16 bf16x8;
typedef __attribute__((ext_vector_type(4))) float  f32x4;

// ---------- kernel 1: W fp32 -> bf16 in A-fragment order (unchanged) ----------
__global__ __launch_bounds__(256)
void w_repack_kernel(const float* __restrict__ W, bf16* __restrict__ Wb) {
    const int t = blockIdx.x * 256 + threadIdx.x;       // 66*12*64 = 50688
    if (t >= NK32 * 12 * 64) return;
    const int lane = t & 63;
    const int gmt  = (t >> 6) % 12;
    const int ks   = t / (12 * 64);
    const int row  = gmt * 16 + (lane & 15);
    const int k    = ks * BK + (lane >> 4) * 8;
    const float* src = W + (size_t)row * CIN + k;
    f32x4 a = *(const f32x4*)src;
    f32x4 c = *(const f32x4*)(src + 4);
    bf16x8 o;
    #pragma unroll
    for (int j = 0; j < 4; j++) { o[j] = (bf16)a[j]; o[j + 4] = (bf16)c[j]; }
    *(bf16x8*)(Wb + (size_t)t * 8) = o;
}

// ---------- kernel 2: fused BN+ReLU+pack+GEMM over one K-half ----------
__global__ __launch_bounds__(512, 4)
void fused_kernel(const float* __restrict__ x,
                  const float* __restrict__ gamma,
                  const float* __restrict__ beta,
                  const float* __restrict__ rmean,
                  const float* __restrict__ rvar,
                  const bf16* __restrict__ Wb,
                  float* __restrict__ par)
{
    __shared__ float2 ss[CHALF + 2];                 // half's BN params (+pad)
    __shared__ __align__(16) bf16 bt[2][SLAB];       // double-buffered tile

    const int tid = threadIdx.x;
    const int b   = blockIdx.x >> 1;                 // image
    const int kh  = blockIdx.x & 1;                  // K-half
    const int g0  = kh * HALF;                       // first global granule
    const int c0  = kh * CHALF;                      // first channel

    // BN params for this half -> LDS
    for (int c = tid; c < CHALF; c += 512) {
        const int gc = c0 + c;
        float inv = rsqrtf(rvar[gc] + EPSV);
        float s   = gamma[gc] * inv;
        ss[c] = make_float2(s, beta[gc] - rmean[gc] * s);
    }
    if (tid < 2) ss[CHALF + tid] = make_float2(0.f, 0.f);

    // ---- staging role: threads 0..195 own 8 consecutive floats of a slab
    const bool act = tid < (SLAB / 8);               // 196
    const int fb  = tid * 8;
    const int cl0 = fb / HWS;                        // channel-in-slab 0..31
    const int hw0 = fb - cl0 * HWS;
    const int jw  = (hw0 + 8 <= HWS) ? 8 : (HWS - hw0);
    int addrs[8];
    #pragma unroll
    for (int j = 0; j < 8; j++) {
        int hw = hw0 + j, cl = cl0;
        if (hw >= HWS) { hw -= HWS; cl += 1; }
        const int rot = ((cl >> 3) + (hw >> 2)) & 3;      // bank swizzle
        addrs[j] = hw * BK + rot * 8 + (cl & 7);
    }
    const float* xs = x + (size_t)b * (CIN * HWS) + (size_t)c0 * HWS + fb;

    // ---- compute role: 8 waves = 4 M-groups x 2 N-groups (R8-identical)
    const int lane = tid & 63;
    const int wv   = tid >> 6;
    const int mg   = wv & 3;          // 48 Cout rows
    const int ng   = wv >> 2;         // 32 hw cols
    const int l15  = lane & 15;
    const int q    = lane >> 4;

    const int hwc0 = ng * 32 + l15;               // <= 47, always valid
    int hwc1 = ng * 32 + 16 + l15;
    if (hwc1 > 48) hwc1 = 48;                     // dup col 48 (discarded)
    const int bad0 = hwc0 * BK + ((q + (hwc0 >> 2)) & 3) * 8;
    const int bad1 = hwc1 * BK + ((q + (hwc1 >> 2)) & 3) * 8;

    const bf16* apL = Wb + (size_t)(mg * 3) * 512 + (size_t)lane * 8;

    f32x4 acc[3][2];
    #pragma unroll
    for (int mt = 0; mt < 3; mt++) { acc[mt][0] = (f32x4)(0.f); acc[mt][1] = (f32x4)(0.f); }

    // prologue: slab0 temp + parity x prefetch (slabs 1,2); A parity preload
    f32x4 t0 = (f32x4)(0.f), t1 = (f32x4)(0.f);
    f32x4 xvA0 = (f32x4)(0.f), xvA1 = (f32x4)(0.f);
    f32x4 xvB0 = (f32x4)(0.f), xvB1 = (f32x4)(0.f);
    if (act) {
        t0   = *(const f32x4*)(xs);
        t1   = *(const f32x4*)(xs + 4);
        xvA0 = *(const f32x4*)(xs + SLAB);
        xvA1 = *(const f32x4*)(xs + SLAB + 4);
        xvB0 = *(const f32x4*)(xs + 2 * SLAB);
        xvB1 = *(const f32x4*)(xs + 2 * SLAB + 4);
    }
    bf16x8 arE[3], arO[3];
    #pragma unroll
    for (int mt = 0; mt < 3; mt++) {
        arE[mt] = *(const bf16x8*)(apL + (size_t)g0 * 6144 + (size_t)(mt * 512));
        arO[mt] = *(const bf16x8*)(apL + (size_t)(g0 + 1) * 6144 + (size_t)(mt * 512));
    }

    __syncthreads();   // ss ready

    // stage slab 0 into bt[0]
    if (act) {
        const float2 s0 = ss[cl0];
        const float2 s1 = ss[cl0 + 1];
        #pragma unroll
        for (int j = 0; j < 8; j++) {
            const float xj = (j < 4) ? t0[j] : t1[j - 4];
            const float sc = (j >= jw) ? s1.x : s0.x;
            const float sh = (j >= jw) ? s1.y : s0.y;
            bt[0][addrs[j]] = (bf16)fmaxf(fmaf(xj, sc, sh), 0.f);
        }
    }
    asm volatile("s_waitcnt lgkmcnt(0)" ::: "memory");
    __builtin_amdgcn_s_barrier();
    __builtin_amdgcn_sched_barrier(0);

    // one local granule g (0..32): read bt[g&1]; stage slab g+1 -> bt[g&1^1];
    // x prefetch g+3 into this parity's slot; barrier; 6 MFMA; A reload g+2.
    auto STEP = [&](int p, int g, f32x4& xv0, f32x4& xv1, bf16x8 (&ar)[3]) {
        const bf16x8 b0 = *(const bf16x8*)&bt[p][bad0];
        const bf16x8 b1 = *(const bf16x8*)&bt[p][bad1];
        if (act) {
            int sl = g + 1; if (sl > HALF - 1) sl = HALF - 1;   // tail-safe
            const int cb = sl * BK;
            const float2 s0 = ss[cb + cl0];
            const float2 s1 = ss[cb + cl0 + 1];
            #pragma unroll
            for (int j = 0; j < 8; j++) {
                const float xj = (j < 4) ? xv0[j] : xv1[j - 4];
                const float sc = (j >= jw) ? s1.x : s0.x;
                const float sh = (j >= jw) ? s1.y : s0.y;
                bt[p ^ 1][addrs[j]] = (bf16)fmaxf(fmaf(xj, sc, sh), 0.f);
            }
            int ln = g + 3; if (ln > HALF - 1) ln = HALF - 1;
            xv0 = *(const f32x4*)(xs + (size_t)ln * SLAB);
            xv1 = *(const f32x4*)(xs + (size_t)ln * SLAB + 4);
        }
        asm volatile("s_waitcnt lgkmcnt(0)" ::: "memory");
        __builtin_amdgcn_s_barrier();
        __builtin_amdgcn_sched_barrier(0);
        #pragma unroll
        for (int mt = 0; mt < 3; mt++) {
            acc[mt][0] = __builtin_amdgcn_mfma_f32_16x16x32_bf16(ar[mt], b0, acc[mt][0], 0, 0, 0);
            acc[mt][1] = __builtin_amdgcn_mfma_f32_16x16x32_bf16(ar[mt], b1, acc[mt][1], 0, 0, 0);
        }
        int tk = g + 2; if (tk > HALF - 1) tk = HALF - 1;
        #pragma unroll
        for (int mt = 0; mt < 3; mt++)
            ar[mt] = *(const bf16x8*)(apL + (size_t)(g0 + tk) * 6144 + (size_t)(mt * 512));
    };

    // 16 parity pairs + 1 even tail = 33 granules. Rolled; ring slots static.
    #pragma unroll 1
    for (int it = 0; it < HALF / 2; ++it) {
        STEP(0, 2 * it,     xvA0, xvA1, arE);
        STEP(1, 2 * it + 1, xvB0, xvB1, arO);
    }
    STEP(0, HALF - 1, xvA0, xvA1, arE);

    // epilogue: partial sums -> par[kh][b][row][hw]. Disjoint stores.
    float* ob = par + ((size_t)kh * 256 + b) * OUTEL;
    const int hw1 = ng * 32 + 16 + l15;            // unclamped for predicate
    #pragma unroll
    for (int mt = 0; mt < 3; mt++) {
        const int row0 = mg * 48 + mt * 16 + q * 4;
        #pragma unroll
        for (int r = 0; r < 4; r++)
            ob[(size_t)(row0 + r) * HWS + hwc0] = acc[mt][0][r];
        if (hw1 < HWS) {
            #pragma unroll
            for (int r = 0; r < 4; r++)
                ob[(size_t)(row0 + r) * HWS + hw1] = acc[mt][1][r];
        }
    }
}

// ---------- kernel 3: sum the two K-half partials ----------
__global__ __launch_bounds__(256)
void add_kernel(const float* __restrict__ par, float* __restrict__ out) {
    const size_t i = (size_t)blockIdx.x * 256 + threadIdx.x;   // f32x4 index
    const size_t n4 = (size_t)256 * OUTEL / 4;                 // 602112
    if (i >= n4) return;
    const f32x4 a = *(const f32x4*)(par + i * 4);
    const f32x4 c = *(const f32x4*)(par + (size_t)256 * OUTEL + i * 4);
    f32x4 o;
    #pragma unroll
    for (int j = 0; j < 4; j++) o[j] = a[j] + c[j];
    *(f32x4*)(out + i * 4) = o;
}

extern "C" void kernel_launch(void* const* d_in, const int* in_sizes, int n_in,
                              void* d_out, int out_size, void* d_ws, size_t ws_size,
                              hipStream_t stream) {
    const float* x     = (const float*)d_in[0];
    const float* gamma = (const float*)d_in[1];
    const float* beta  = (const float*)d_in[2];
    const float* rmean = (const float*)d_in[3];
    const float* rvar  = (const float*)d_in[4];
    const float* W     = (const float*)d_in[5];
    float* out = (float*)d_out;

    bf16*  Wb  = (bf16*)d_ws;                              // 811,008 B
    float* par = (float*)((char*)d_ws + (1 << 20));        // 2 x 9.63 MB partials

    w_repack_kernel<<<dim3(198), dim3(256), 0, stream>>>(W, Wb);
    fused_kernel<<<dim3(512), dim3(512), 0, stream>>>(
        x, gamma, beta, rmean, rvar, Wb, par);
    add_kernel<<<dim3((256 * OUTEL / 4 + 255) / 256), dim3(256), 0, stream>>>(par, out);
}